// Round 1
// baseline (2090.389 us; speedup 1.0000x reference)
//
#include <hip/hip_runtime.h>
#include <hip/hip_bf16.h>

#define N_ENTITIES 300000
#define N_ITEMS    150000
#define N_USERS    150000
#define N_EDGES    2000000
#define N_INTER    2000000
#define D          64

// ---------------------------------------------------------------------------
// Kernel A: neigh_relation_emb = entity_emb[tail] * weight[edge_type],
// scatter-add into ent_sums[head], count into ent_cnt[head].
// 64 consecutive threads = 64 dims of one edge (coalesced 256B per edge).
// ---------------------------------------------------------------------------
__global__ void scatter_kg_kernel(const float* __restrict__ entity_emb,
                                  const int* __restrict__ edge_head,
                                  const int* __restrict__ edge_tail,
                                  const int* __restrict__ edge_type,
                                  const float* __restrict__ weight,
                                  float* __restrict__ ent_sums,
                                  float* __restrict__ ent_cnt) {
    long long idx = (long long)blockIdx.x * blockDim.x + threadIdx.x;
    int e = (int)(idx >> 6);
    int d = (int)(idx & 63);
    if (e >= N_EDGES) return;
    int head = edge_head[e];
    int tail = edge_tail[e];
    int t    = edge_type[e];
    float v = entity_emb[(long long)tail * D + d] * weight[t * D + d];
    atomicAdd(&ent_sums[(long long)head * D + d], v);
    if (d == 0) atomicAdd(&ent_cnt[head], 1.0f);
}

// ---------------------------------------------------------------------------
// Kernel B: scatter user_emb[mat_row] into item_sums[mat_col] + counts.
// ---------------------------------------------------------------------------
__global__ void scatter_int_kernel(const float* __restrict__ user_emb,
                                   const int* __restrict__ mat_row,
                                   const int* __restrict__ mat_col,
                                   float* __restrict__ item_sums,
                                   float* __restrict__ item_cnt) {
    long long idx = (long long)blockIdx.x * blockDim.x + threadIdx.x;
    int e = (int)(idx >> 6);
    int d = (int)(idx & 63);
    if (e >= N_INTER) return;
    int r = mat_row[e];
    int c = mat_col[e];
    float v = user_emb[(long long)r * D + d];
    atomicAdd(&item_sums[(long long)c * D + d], v);
    if (d == 0) atomicAdd(&item_cnt[c], 1.0f);
}

// ---------------------------------------------------------------------------
// Kernel C: per item i (one wave each):
//   item_kg  = ent_sums[i]/max(cnt,1);  item_int = item_sums[i]/max(cnt,1)
//   gi = sigmoid(item_kg @ g1^T + item_int @ g2^T)   (64x64 GEMV via shuffles)
//   fusion = gi*item_kg + (1-gi)*item_int
// Writes: out_final[i] (=fusion), out_item_kg[i], out_item_int[i].
// Gate matrices staged in LDS with stride 65 (2-way bank aliasing = free).
// ---------------------------------------------------------------------------
__global__ __launch_bounds__(256) void fuse_kernel(
        const float* __restrict__ ent_sums, const float* __restrict__ ent_cnt,
        const float* __restrict__ item_sums, const float* __restrict__ item_cnt,
        const float* __restrict__ g1, const float* __restrict__ g2,
        float* __restrict__ out_final,
        float* __restrict__ out_item_kg,
        float* __restrict__ out_item_int) {
    __shared__ float s_g1[64 * 65];
    __shared__ float s_g2[64 * 65];
    for (int i = threadIdx.x; i < 64 * 64; i += 256) {
        int r = i >> 6, c = i & 63;
        s_g1[r * 65 + c] = g1[i];
        s_g2[r * 65 + c] = g2[i];
    }
    __syncthreads();

    int wave = threadIdx.x >> 6;
    int lane = threadIdx.x & 63;
    int item = blockIdx.x * 4 + wave;
    if (item >= N_ITEMS) return;

    float kc = ent_cnt[item];  kc = kc > 1.0f ? kc : 1.0f;
    float ic = item_cnt[item]; ic = ic > 1.0f ? ic : 1.0f;
    float kg = ent_sums[(long long)item * D + lane] / kc;
    float ii = item_sums[(long long)item * D + lane] / ic;

    // out[d] = sum_k kg[k]*g1[d][k] + ii[k]*g2[d][k]   (lane == d)
    float acc = 0.0f;
    #pragma unroll 8
    for (int k = 0; k < 64; ++k) {
        float a = __shfl(kg, k);
        float b = __shfl(ii, k);
        acc += a * s_g1[lane * 65 + k] + b * s_g2[lane * 65 + k];
    }
    float gi  = 1.0f / (1.0f + __expf(-acc));
    float fus = gi * kg + (1.0f - gi) * ii;

    long long o = (long long)item * D + lane;
    out_final[o]    = fus;
    out_item_kg[o]  = kg;
    out_item_int[o] = ii;
}

// ---------------------------------------------------------------------------
// Kernel D: att_kg_agg rows -> final_entity_agg[N_ITEMS:]
// ---------------------------------------------------------------------------
__global__ void att_kernel(const float* __restrict__ ent_sums,
                           const float* __restrict__ ent_cnt,
                           float* __restrict__ out_final) {
    long long idx = (long long)blockIdx.x * blockDim.x + threadIdx.x;
    const long long total = (long long)(N_ENTITIES - N_ITEMS) * D;
    if (idx >= total) return;
    int row = (int)(idx >> 6);
    int d   = (int)(idx & 63);
    int ent = N_ITEMS + row;
    float c = ent_cnt[ent]; c = c > 1.0f ? c : 1.0f;
    out_final[(long long)ent * D + d] = ent_sums[(long long)ent * D + d] / c;
}

// ---------------------------------------------------------------------------
// Kernel E: user_agg = segment_sum(fusion[mat_col], mat_row)
// ---------------------------------------------------------------------------
__global__ void user_scatter_kernel(const float* __restrict__ fusion,
                                    const int* __restrict__ mat_row,
                                    const int* __restrict__ mat_col,
                                    float* __restrict__ user_agg) {
    long long idx = (long long)blockIdx.x * blockDim.x + threadIdx.x;
    int e = (int)(idx >> 6);
    int d = (int)(idx & 63);
    if (e >= N_INTER) return;
    int r = mat_row[e];
    int c = mat_col[e];
    float v = fusion[(long long)c * D + d];
    atomicAdd(&user_agg[(long long)r * D + d], v);
}

extern "C" void kernel_launch(void* const* d_in, const int* in_sizes, int n_in,
                              void* d_out, int out_size, void* d_ws, size_t ws_size,
                              hipStream_t stream) {
    const float* entity_emb = (const float*)d_in[0];
    const float* user_emb   = (const float*)d_in[1];
    const int*   edge_index = (const int*)d_in[2];   // (2, N_EDGES)
    const int*   edge_type  = (const int*)d_in[3];
    const int*   mat_row    = (const int*)d_in[4];
    const int*   mat_col    = (const int*)d_in[5];
    const float* weight     = (const float*)d_in[6];
    const float* g1         = (const float*)d_in[7];
    const float* g2         = (const float*)d_in[8];

    const int* edge_head = edge_index;
    const int* edge_tail = edge_index + N_EDGES;

    float* out = (float*)d_out;
    // out layout (floats): final_entity_agg[300000*64] | user_agg[150000*64]
    //                      | item_kg_agg[150000*64]   | item_int_agg[150000*64]
    float* out_final    = out;
    float* out_user     = out + (long long)N_ENTITIES * D;
    float* out_item_kg  = out_user + (long long)N_USERS * D;
    float* out_item_int = out_item_kg + (long long)N_ITEMS * D;

    // workspace layout (floats): ent_sums | item_sums | ent_cnt | item_cnt
    float* ent_sums  = (float*)d_ws;
    float* item_sums = ent_sums + (long long)N_ENTITIES * D;
    float* ent_cnt   = item_sums + (long long)N_ITEMS * D;
    float* item_cnt  = ent_cnt + N_ENTITIES;

    const size_t ws_floats = (size_t)N_ENTITIES * D + (size_t)N_ITEMS * D
                           + N_ENTITIES + N_ITEMS;
    hipMemsetAsync(d_ws, 0, ws_floats * sizeof(float), stream);
    hipMemsetAsync(out_user, 0, (size_t)N_USERS * D * sizeof(float), stream);

    // A: KG scatter-mean numerators
    {
        long long threads = (long long)N_EDGES * D;
        int blocks = (int)((threads + 255) / 256);
        scatter_kg_kernel<<<blocks, 256, 0, stream>>>(
            entity_emb, edge_head, edge_tail, edge_type, weight, ent_sums, ent_cnt);
    }
    // B: interaction scatter-mean numerators
    {
        long long threads = (long long)N_INTER * D;
        int blocks = (int)((threads + 255) / 256);
        scatter_int_kernel<<<blocks, 256, 0, stream>>>(
            user_emb, mat_row, mat_col, item_sums, item_cnt);
    }
    // C: normalize + gate + fusion (one wave per item)
    {
        int blocks = (N_ITEMS + 3) / 4;
        fuse_kernel<<<blocks, 256, 0, stream>>>(
            ent_sums, ent_cnt, item_sums, item_cnt, g1, g2,
            out_final, out_item_kg, out_item_int);
    }
    // D: attribute entities -> final_entity_agg[N_ITEMS:]
    {
        long long threads = (long long)(N_ENTITIES - N_ITEMS) * D;
        int blocks = (int)((threads + 255) / 256);
        att_kernel<<<blocks, 256, 0, stream>>>(ent_sums, ent_cnt, out_final);
    }
    // E: user_agg scatter-sum of fused item rows
    {
        long long threads = (long long)N_INTER * D;
        int blocks = (int)((threads + 255) / 256);
        user_scatter_kernel<<<blocks, 256, 0, stream>>>(
            out_final, mat_row, mat_col, out_user);
    }
}

// Round 2
// 1732.944 us; speedup vs baseline: 1.2063x; 1.2063x over previous
//
#include <hip/hip_runtime.h>
#include <hip/hip_bf16.h>

#define N_ENTITIES 300000
#define N_ITEMS    150000
#define N_USERS    150000
#define N_EDGES    2000000
#define N_INTER    2000000
#define D          64

// ===========================================================================
// Phase 1: counting-sort machinery (int atomics only — 4B each, cheap)
// ===========================================================================

// One pass over both edge lists (same length): histogram all three keys.
__global__ void hist_kernel(const int* __restrict__ head,
                            const int* __restrict__ mat_col,
                            const int* __restrict__ mat_row,
                            int* __restrict__ cnt_ent,
                            int* __restrict__ cnt_item,
                            int* __restrict__ cnt_user) {
    int e = blockIdx.x * 256 + threadIdx.x;
    if (e >= N_EDGES) return;
    atomicAdd(&cnt_ent[head[e]], 1);
    atomicAdd(&cnt_item[mat_col[e]], 1);
    atomicAdd(&cnt_user[mat_row[e]], 1);
}

// Block-wise scan: each block scans 1024 elements (256 thr x 4), writes
// inclusive partial results + per-block total.
__global__ __launch_bounds__(256) void scan_partial(const int* __restrict__ in,
                                                    int* __restrict__ incl,
                                                    int* __restrict__ bsums,
                                                    int n) {
    __shared__ int lds[256];
    int t = threadIdx.x;
    int base = blockIdx.x * 1024 + t * 4;
    int v0 = (base + 0 < n) ? in[base + 0] : 0;
    int v1 = (base + 1 < n) ? in[base + 1] : 0;
    int v2 = (base + 2 < n) ? in[base + 2] : 0;
    int v3 = (base + 3 < n) ? in[base + 3] : 0;
    int s = v0 + v1 + v2 + v3;
    lds[t] = s;
    __syncthreads();
    for (int off = 1; off < 256; off <<= 1) {
        int x = (t >= off) ? lds[t - off] : 0;
        __syncthreads();
        lds[t] += x;
        __syncthreads();
    }
    int excl = lds[t] - s;
    if (base + 0 < n) incl[base + 0] = excl + v0;
    if (base + 1 < n) incl[base + 1] = excl + v0 + v1;
    if (base + 2 < n) incl[base + 2] = excl + v0 + v1 + v2;
    if (base + 3 < n) incl[base + 3] = excl + s;
    if (t == 255) bsums[blockIdx.x] = lds[255];
}

// Single-block scan of block sums (nb <= 293 < 512).
__global__ __launch_bounds__(512) void scan_bsums(int* __restrict__ bsums, int nb) {
    __shared__ int lds[512];
    int t = threadIdx.x;
    lds[t] = (t < nb) ? bsums[t] : 0;
    __syncthreads();
    for (int off = 1; off < 512; off <<= 1) {
        int x = (t >= off) ? lds[t - off] : 0;
        __syncthreads();
        lds[t] += x;
        __syncthreads();
    }
    if (t < nb) bsums[t] = lds[t];
}

// off[i+1] = global inclusive; off[0]=0; cursor[i] = global exclusive.
__global__ void scan_finalize(const int* __restrict__ incl,
                              const int* __restrict__ bsums,
                              const int* __restrict__ cnt,
                              int* __restrict__ off,
                              int* __restrict__ cur,
                              int n) {
    int i = blockIdx.x * 256 + threadIdx.x;
    if (i >= n) return;
    int b = i >> 10;
    int add = (b > 0) ? bsums[b - 1] : 0;
    int gincl = incl[i] + add;
    off[i + 1] = gincl;
    cur[i] = gincl - cnt[i];
    if (i == 0) off[0] = 0;
}

// Permutation scatter: materialize bucket-sorted payloads.
__global__ void scatter_build_kg(const int* __restrict__ head,
                                 const int* __restrict__ tail,
                                 const int* __restrict__ type,
                                 int* __restrict__ cur_ent,
                                 int* __restrict__ tail_sorted,
                                 int* __restrict__ type_sorted) {
    int e = blockIdx.x * 256 + threadIdx.x;
    if (e >= N_EDGES) return;
    int pos = atomicAdd(&cur_ent[head[e]], 1);
    tail_sorted[pos] = tail[e];
    type_sorted[pos] = type[e];
}

__global__ void scatter_build_int(const int* __restrict__ mat_row,
                                  const int* __restrict__ mat_col,
                                  int* __restrict__ cur_item,
                                  int* __restrict__ cur_user,
                                  int* __restrict__ row_sorted,
                                  int* __restrict__ col_sorted) {
    int e = blockIdx.x * 256 + threadIdx.x;
    if (e >= N_INTER) return;
    int r = mat_row[e], c = mat_col[e];
    int p1 = atomicAdd(&cur_item[c], 1);
    row_sorted[p1] = r;
    int p2 = atomicAdd(&cur_user[r], 1);
    col_sorted[p2] = c;
}

// ===========================================================================
// Phase 2: gather-based aggregation — one wave per destination row, lane=dim.
// ===========================================================================

__global__ __launch_bounds__(256) void agg_ent_kernel(
        const float* __restrict__ entity_emb, const float* __restrict__ weight,
        const int* __restrict__ off, const int* __restrict__ tail_sorted,
        const int* __restrict__ type_sorted,
        float* __restrict__ out_item_kg, float* __restrict__ out_final) {
    int wave = threadIdx.x >> 6, lane = threadIdx.x & 63;
    int ent = blockIdx.x * 4 + wave;
    if (ent >= N_ENTITIES) return;
    int s = off[ent], e = off[ent + 1];
    int cnt = e - s;
    float acc = 0.0f;
    for (int base = s; base < e; base += 64) {
        int m = e - base; if (m > 64) m = 64;
        int tl = (lane < m) ? tail_sorted[base + lane] : 0;
        int ty = (lane < m) ? type_sorted[base + lane] : 0;
        for (int j = 0; j < m; ++j) {
            int t = __shfl(tl, j);
            int w = __shfl(ty, j);
            acc += entity_emb[(long long)t * D + lane] * weight[w * D + lane];
        }
    }
    float mean = acc / (float)(cnt > 1 ? cnt : 1);
    if (ent < N_ITEMS) out_item_kg[(long long)ent * D + lane] = mean;
    else               out_final[(long long)ent * D + lane]   = mean;
}

__global__ __launch_bounds__(256) void agg_item_kernel(
        const float* __restrict__ user_emb,
        const int* __restrict__ off, const int* __restrict__ row_sorted,
        float* __restrict__ out_item_int) {
    int wave = threadIdx.x >> 6, lane = threadIdx.x & 63;
    int item = blockIdx.x * 4 + wave;
    if (item >= N_ITEMS) return;
    int s = off[item], e = off[item + 1];
    int cnt = e - s;
    float acc = 0.0f;
    for (int base = s; base < e; base += 64) {
        int m = e - base; if (m > 64) m = 64;
        int rw = (lane < m) ? row_sorted[base + lane] : 0;
        for (int j = 0; j < m; ++j) {
            int r = __shfl(rw, j);
            acc += user_emb[(long long)r * D + lane];
        }
    }
    out_item_int[(long long)item * D + lane] = acc / (float)(cnt > 1 ? cnt : 1);
}

__global__ __launch_bounds__(256) void fuse_kernel(
        const float* __restrict__ item_kg, const float* __restrict__ item_int,
        const float* __restrict__ g1, const float* __restrict__ g2,
        float* __restrict__ out_final) {
    __shared__ float s_g1[64 * 65];
    __shared__ float s_g2[64 * 65];
    for (int i = threadIdx.x; i < 64 * 64; i += 256) {
        int r = i >> 6, c = i & 63;
        s_g1[r * 65 + c] = g1[i];
        s_g2[r * 65 + c] = g2[i];
    }
    __syncthreads();

    int wave = threadIdx.x >> 6, lane = threadIdx.x & 63;
    int item = blockIdx.x * 4 + wave;
    if (item >= N_ITEMS) return;

    long long o = (long long)item * D + lane;
    float kg = item_kg[o];
    float ii = item_int[o];

    float acc = 0.0f;
    #pragma unroll 8
    for (int k = 0; k < 64; ++k) {
        float a = __shfl(kg, k);
        float b = __shfl(ii, k);
        acc += a * s_g1[lane * 65 + k] + b * s_g2[lane * 65 + k];
    }
    float gi = 1.0f / (1.0f + __expf(-acc));
    out_final[o] = gi * kg + (1.0f - gi) * ii;
}

__global__ __launch_bounds__(256) void agg_user_kernel(
        const float* __restrict__ fusion,   // = out_final[:N_ITEMS]
        const int* __restrict__ off, const int* __restrict__ col_sorted,
        float* __restrict__ out_user) {
    int wave = threadIdx.x >> 6, lane = threadIdx.x & 63;
    int user = blockIdx.x * 4 + wave;
    if (user >= N_USERS) return;
    int s = off[user], e = off[user + 1];
    float acc = 0.0f;
    for (int base = s; base < e; base += 64) {
        int m = e - base; if (m > 64) m = 64;
        int cl = (lane < m) ? col_sorted[base + lane] : 0;
        for (int j = 0; j < m; ++j) {
            int c = __shfl(cl, j);
            acc += fusion[(long long)c * D + lane];
        }
    }
    out_user[(long long)user * D + lane] = acc;   // segment_sum (no mean)
}

// ===========================================================================

extern "C" void kernel_launch(void* const* d_in, const int* in_sizes, int n_in,
                              void* d_out, int out_size, void* d_ws, size_t ws_size,
                              hipStream_t stream) {
    const float* entity_emb = (const float*)d_in[0];
    const float* user_emb   = (const float*)d_in[1];
    const int*   edge_index = (const int*)d_in[2];   // (2, N_EDGES)
    const int*   edge_type  = (const int*)d_in[3];
    const int*   mat_row    = (const int*)d_in[4];
    const int*   mat_col    = (const int*)d_in[5];
    const float* weight     = (const float*)d_in[6];
    const float* g1         = (const float*)d_in[7];
    const float* g2         = (const float*)d_in[8];

    const int* edge_head = edge_index;
    const int* edge_tail = edge_index + N_EDGES;

    float* out = (float*)d_out;
    float* out_final    = out;                                   // [300000,64]
    float* out_user     = out + (long long)N_ENTITIES * D;       // [150000,64]
    float* out_item_kg  = out_user + (long long)N_USERS * D;     // [150000,64]
    float* out_item_int = out_item_kg + (long long)N_ITEMS * D;  // [150000,64]

    // ---- workspace layout (all int32) ----
    int* w = (int*)d_ws;
    int* cnt_ent   = w;                    w += N_ENTITIES;   // zeroed
    int* cnt_item  = w;                    w += N_ITEMS;      // zeroed
    int* cnt_user  = w;                    w += N_USERS;      // zeroed
    int* off_ent   = w;                    w += N_ENTITIES + 1;
    int* off_item  = w;                    w += N_ITEMS + 1;
    int* off_user  = w;                    w += N_USERS + 1;
    int* cur_ent   = w;                    w += N_ENTITIES;
    int* cur_item  = w;                    w += N_ITEMS;
    int* cur_user  = w;                    w += N_USERS;
    int* incl_tmp  = w;                    w += N_ENTITIES;   // shared by 3 scans
    int* bsums     = w;                    w += 512;          // shared by 3 scans
    int* tail_sorted = w;                  w += N_EDGES;
    int* type_sorted = w;                  w += N_EDGES;
    int* row_sorted  = w;                  w += N_INTER;
    int* col_sorted  = w;                  w += N_INTER;

    // zero the three count arrays (contiguous at the front of ws)
    hipMemsetAsync(d_ws, 0, (size_t)(N_ENTITIES + N_ITEMS + N_USERS) * sizeof(int),
                   stream);

    const int EB = (N_EDGES + 255) / 256;

    // 1) histograms (both lists are 2M long — one pass)
    hist_kernel<<<EB, 256, 0, stream>>>(edge_head, mat_col, mat_row,
                                        cnt_ent, cnt_item, cnt_user);

    // 2) three prefix sums -> offsets + cursors
    {
        int n = N_ENTITIES, nb = (n + 1023) / 1024;
        scan_partial<<<nb, 256, 0, stream>>>(cnt_ent, incl_tmp, bsums, n);
        scan_bsums<<<1, 512, 0, stream>>>(bsums, nb);
        scan_finalize<<<(n + 255) / 256, 256, 0, stream>>>(incl_tmp, bsums,
                                                           cnt_ent, off_ent, cur_ent, n);
    }
    {
        int n = N_ITEMS, nb = (n + 1023) / 1024;
        scan_partial<<<nb, 256, 0, stream>>>(cnt_item, incl_tmp, bsums, n);
        scan_bsums<<<1, 512, 0, stream>>>(bsums, nb);
        scan_finalize<<<(n + 255) / 256, 256, 0, stream>>>(incl_tmp, bsums,
                                                           cnt_item, off_item, cur_item, n);
    }
    {
        int n = N_USERS, nb = (n + 1023) / 1024;
        scan_partial<<<nb, 256, 0, stream>>>(cnt_user, incl_tmp, bsums, n);
        scan_bsums<<<1, 512, 0, stream>>>(bsums, nb);
        scan_finalize<<<(n + 255) / 256, 256, 0, stream>>>(incl_tmp, bsums,
                                                           cnt_user, off_user, cur_user, n);
    }

    // 3) bucket-sorted payloads
    scatter_build_kg<<<EB, 256, 0, stream>>>(edge_head, edge_tail, edge_type,
                                             cur_ent, tail_sorted, type_sorted);
    scatter_build_int<<<EB, 256, 0, stream>>>(mat_row, mat_col,
                                              cur_item, cur_user,
                                              row_sorted, col_sorted);

    // 4) gather aggregations
    agg_ent_kernel<<<(N_ENTITIES + 3) / 4, 256, 0, stream>>>(
        entity_emb, weight, off_ent, tail_sorted, type_sorted,
        out_item_kg, out_final);
    agg_item_kernel<<<(N_ITEMS + 3) / 4, 256, 0, stream>>>(
        user_emb, off_item, row_sorted, out_item_int);
    fuse_kernel<<<(N_ITEMS + 3) / 4, 256, 0, stream>>>(
        out_item_kg, out_item_int, g1, g2, out_final);
    agg_user_kernel<<<(N_USERS + 3) / 4, 256, 0, stream>>>(
        out_final, off_user, col_sorted, out_user);
}

// Round 3
// 1400.664 us; speedup vs baseline: 1.4924x; 1.2372x over previous
//
#include <hip/hip_runtime.h>

#define N_ENTITIES 300000
#define N_ITEMS    150000
#define N_USERS    150000
#define N_EDGES    2000000
#define N_INTER    2000000
#define D          64
#define N_TOT      (N_ENTITIES + N_ITEMS + N_USERS)   // 600000

// ===========================================================================
// Pass 1: histogram + rank. The atomic's return value IS the within-bucket
// rank, so the later payload scatter needs no atomics at all.
// Counters are one concatenated array: [ent(300K) | item(150K) | user(150K)].
// ===========================================================================
__global__ void hist_rank_kernel(const int* __restrict__ head,
                                 const int* __restrict__ mat_col,
                                 const int* __restrict__ mat_row,
                                 int* __restrict__ cnt,
                                 int* __restrict__ r_ent,
                                 int* __restrict__ r_item,
                                 int* __restrict__ r_user) {
    int e = blockIdx.x * 256 + threadIdx.x;
    if (e >= N_EDGES) return;
    int h = head[e], c = mat_col[e], r = mat_row[e];
    int a0 = atomicAdd(&cnt[h], 1);
    int a1 = atomicAdd(&cnt[N_ENTITIES + c], 1);
    int a2 = atomicAdd(&cnt[N_ENTITIES + N_ITEMS + r], 1);
    r_ent[e]  = a0;
    r_item[e] = a1;
    r_user[e] = a2;
}

// ===========================================================================
// One scan over the whole 600K concatenated count array.
// ===========================================================================
__global__ __launch_bounds__(256) void scan_partial(const int* __restrict__ in,
                                                    int* __restrict__ incl,
                                                    int* __restrict__ bsums,
                                                    int n) {
    __shared__ int lds[256];
    int t = threadIdx.x;
    int base = blockIdx.x * 1024 + t * 4;
    int v0 = (base + 0 < n) ? in[base + 0] : 0;
    int v1 = (base + 1 < n) ? in[base + 1] : 0;
    int v2 = (base + 2 < n) ? in[base + 2] : 0;
    int v3 = (base + 3 < n) ? in[base + 3] : 0;
    int s = v0 + v1 + v2 + v3;
    lds[t] = s;
    __syncthreads();
    for (int off = 1; off < 256; off <<= 1) {
        int x = (t >= off) ? lds[t - off] : 0;
        __syncthreads();
        lds[t] += x;
        __syncthreads();
    }
    int excl = lds[t] - s;
    if (base + 0 < n) incl[base + 0] = excl + v0;
    if (base + 1 < n) incl[base + 1] = excl + v0 + v1;
    if (base + 2 < n) incl[base + 2] = excl + v0 + v1 + v2;
    if (base + 3 < n) incl[base + 3] = excl + s;
    if (t == 255) bsums[blockIdx.x] = lds[255];
}

// nb <= 586 < 1024
__global__ __launch_bounds__(1024) void scan_bsums(int* __restrict__ bsums, int nb) {
    __shared__ int lds[1024];
    int t = threadIdx.x;
    lds[t] = (t < nb) ? bsums[t] : 0;
    __syncthreads();
    for (int off = 1; off < 1024; off <<= 1) {
        int x = (t >= off) ? lds[t - off] : 0;
        __syncthreads();
        lds[t] += x;
        __syncthreads();
    }
    if (t < nb) bsums[t] = lds[t];
}

// Split the global inclusive scan back into three offset arrays. Region
// totals are the known constants N_EDGES / 2*N_EDGES.
__global__ void scan_finalize(const int* __restrict__ incl,
                              const int* __restrict__ bsums,
                              int* __restrict__ off_ent,
                              int* __restrict__ off_item,
                              int* __restrict__ off_user) {
    int i = blockIdx.x * 256 + threadIdx.x;
    if (i >= N_TOT) return;
    int b = i >> 10;
    int g = incl[i] + ((b > 0) ? bsums[b - 1] : 0);
    if (i < N_ENTITIES) {
        off_ent[i + 1] = g;
        if (i == 0) { off_ent[0] = 0; }
    } else if (i < N_ENTITIES + N_ITEMS) {
        off_item[i - N_ENTITIES + 1] = g - N_EDGES;
        if (i == N_ENTITIES) { off_item[0] = 0; }
    } else {
        off_user[i - N_ENTITIES - N_ITEMS + 1] = g - 2 * N_EDGES;
        if (i == N_ENTITIES + N_ITEMS) { off_user[0] = 0; }
    }
}

// ===========================================================================
// Pass 2: atomic-free payload scatter. pos = off[key] + rank.
// KG payload packed: tail(19b) | type<<19 — one 4B store instead of two.
// ===========================================================================
__global__ void scatter_all_kernel(const int* __restrict__ head,
                                   const int* __restrict__ tail,
                                   const int* __restrict__ type,
                                   const int* __restrict__ mat_row,
                                   const int* __restrict__ mat_col,
                                   const int* __restrict__ r_ent,
                                   const int* __restrict__ r_item,
                                   const int* __restrict__ r_user,
                                   const int* __restrict__ off_ent,
                                   const int* __restrict__ off_item,
                                   const int* __restrict__ off_user,
                                   int* __restrict__ tt_sorted,
                                   int* __restrict__ row_sorted,
                                   int* __restrict__ col_sorted) {
    int e = blockIdx.x * 256 + threadIdx.x;
    if (e >= N_EDGES) return;
    int h = head[e], t = tail[e], ty = type[e];
    int r = mat_row[e], c = mat_col[e];
    tt_sorted[off_ent[h] + r_ent[e]]   = t | (ty << 19);
    row_sorted[off_item[c] + r_item[e]] = r;
    col_sorted[off_user[r] + r_user[e]] = c;
}

// ===========================================================================
// Gather aggregations — one wave per destination row, lane = dim.
// ===========================================================================
__global__ __launch_bounds__(256) void agg_ent_kernel(
        const float* __restrict__ entity_emb, const float* __restrict__ weight,
        const int* __restrict__ off, const int* __restrict__ tt_sorted,
        float* __restrict__ out_item_kg, float* __restrict__ out_final) {
    int wave = threadIdx.x >> 6, lane = threadIdx.x & 63;
    int ent = blockIdx.x * 4 + wave;
    if (ent >= N_ENTITIES) return;
    int s = off[ent], e = off[ent + 1];
    int cnt = e - s;
    float acc = 0.0f;
    for (int base = s; base < e; base += 64) {
        int m = e - base; if (m > 64) m = 64;
        int tt = (lane < m) ? tt_sorted[base + lane] : 0;
        for (int j = 0; j < m; ++j) {
            int v = __shfl(tt, j);
            int t = v & 0x7FFFF;
            int w = v >> 19;
            acc += entity_emb[(long long)t * D + lane] * weight[w * D + lane];
        }
    }
    float mean = acc / (float)(cnt > 1 ? cnt : 1);
    if (ent < N_ITEMS) out_item_kg[(long long)ent * D + lane] = mean;
    else               out_final[(long long)ent * D + lane]   = mean;
}

// item_int mean + gate + fusion in one kernel (reads item_kg from agg_ent).
__global__ __launch_bounds__(256) void agg_item_fuse_kernel(
        const float* __restrict__ user_emb,
        const int* __restrict__ off, const int* __restrict__ row_sorted,
        const float* __restrict__ item_kg,
        const float* __restrict__ g1, const float* __restrict__ g2,
        float* __restrict__ out_item_int, float* __restrict__ out_final) {
    __shared__ float s_g1[64 * 65];
    __shared__ float s_g2[64 * 65];
    for (int i = threadIdx.x; i < 64 * 64; i += 256) {
        int r = i >> 6, c = i & 63;
        s_g1[r * 65 + c] = g1[i];
        s_g2[r * 65 + c] = g2[i];
    }
    __syncthreads();

    int wave = threadIdx.x >> 6, lane = threadIdx.x & 63;
    int item = blockIdx.x * 4 + wave;
    if (item >= N_ITEMS) return;
    int s = off[item], e = off[item + 1];
    int cnt = e - s;
    float acc = 0.0f;
    for (int base = s; base < e; base += 64) {
        int m = e - base; if (m > 64) m = 64;
        int rw = (lane < m) ? row_sorted[base + lane] : 0;
        for (int j = 0; j < m; ++j) {
            int r = __shfl(rw, j);
            acc += user_emb[(long long)r * D + lane];
        }
    }
    float ii = acc / (float)(cnt > 1 ? cnt : 1);

    long long o = (long long)item * D + lane;
    float kg = item_kg[o];

    float gacc = 0.0f;
    #pragma unroll 8
    for (int k = 0; k < 64; ++k) {
        float a = __shfl(kg, k);
        float b = __shfl(ii, k);
        gacc += a * s_g1[lane * 65 + k] + b * s_g2[lane * 65 + k];
    }
    float gi = 1.0f / (1.0f + __expf(-gacc));
    out_item_int[o] = ii;
    out_final[o]    = gi * kg + (1.0f - gi) * ii;
}

__global__ __launch_bounds__(256) void agg_user_kernel(
        const float* __restrict__ fusion,   // = out_final[:N_ITEMS]
        const int* __restrict__ off, const int* __restrict__ col_sorted,
        float* __restrict__ out_user) {
    int wave = threadIdx.x >> 6, lane = threadIdx.x & 63;
    int user = blockIdx.x * 4 + wave;
    if (user >= N_USERS) return;
    int s = off[user], e = off[user + 1];
    float acc = 0.0f;
    for (int base = s; base < e; base += 64) {
        int m = e - base; if (m > 64) m = 64;
        int cl = (lane < m) ? col_sorted[base + lane] : 0;
        for (int j = 0; j < m; ++j) {
            int c = __shfl(cl, j);
            acc += fusion[(long long)c * D + lane];
        }
    }
    out_user[(long long)user * D + lane] = acc;   // segment_sum (no mean)
}

// ===========================================================================

extern "C" void kernel_launch(void* const* d_in, const int* in_sizes, int n_in,
                              void* d_out, int out_size, void* d_ws, size_t ws_size,
                              hipStream_t stream) {
    const float* entity_emb = (const float*)d_in[0];
    const float* user_emb   = (const float*)d_in[1];
    const int*   edge_index = (const int*)d_in[2];   // (2, N_EDGES)
    const int*   edge_type  = (const int*)d_in[3];
    const int*   mat_row    = (const int*)d_in[4];
    const int*   mat_col    = (const int*)d_in[5];
    const float* weight     = (const float*)d_in[6];
    const float* g1         = (const float*)d_in[7];
    const float* g2         = (const float*)d_in[8];

    const int* edge_head = edge_index;
    const int* edge_tail = edge_index + N_EDGES;

    float* out = (float*)d_out;
    float* out_final    = out;                                   // [300000,64]
    float* out_user     = out + (long long)N_ENTITIES * D;       // [150000,64]
    float* out_item_kg  = out_user + (long long)N_USERS * D;     // [150000,64]
    float* out_item_int = out_item_kg + (long long)N_ITEMS * D;  // [150000,64]

    // ---- workspace layout (all int32) ----
    int* w = (int*)d_ws;
    int* cnt       = w;  w += N_TOT;            // concat [ent|item|user], zeroed
    int* off_ent   = w;  w += N_ENTITIES + 1;
    int* off_item  = w;  w += N_ITEMS + 1;
    int* off_user  = w;  w += N_USERS + 1;
    int* incl_tmp  = w;  w += N_TOT;
    int* bsums     = w;  w += 1024;
    int* r_ent     = w;  w += N_EDGES;
    int* r_item    = w;  w += N_INTER;
    int* r_user    = w;  w += N_INTER;
    int* tt_sorted = w;  w += N_EDGES;
    int* row_sorted= w;  w += N_INTER;
    int* col_sorted= w;  w += N_INTER;

    hipMemsetAsync(cnt, 0, (size_t)N_TOT * sizeof(int), stream);

    const int EB = (N_EDGES + 255) / 256;

    // 1) histogram + within-bucket ranks (the only atomics in the pipeline)
    hist_rank_kernel<<<EB, 256, 0, stream>>>(edge_head, mat_col, mat_row,
                                             cnt, r_ent, r_item, r_user);

    // 2) one concatenated prefix sum -> three offset arrays
    {
        int nb = (N_TOT + 1023) / 1024;
        scan_partial<<<nb, 256, 0, stream>>>(cnt, incl_tmp, bsums, N_TOT);
        scan_bsums<<<1, 1024, 0, stream>>>(bsums, nb);
        scan_finalize<<<(N_TOT + 255) / 256, 256, 0, stream>>>(
            incl_tmp, bsums, off_ent, off_item, off_user);
    }

    // 3) atomic-free payload scatter
    scatter_all_kernel<<<EB, 256, 0, stream>>>(
        edge_head, edge_tail, edge_type, mat_row, mat_col,
        r_ent, r_item, r_user, off_ent, off_item, off_user,
        tt_sorted, row_sorted, col_sorted);

    // 4) gather aggregations
    agg_ent_kernel<<<(N_ENTITIES + 3) / 4, 256, 0, stream>>>(
        entity_emb, weight, off_ent, tt_sorted, out_item_kg, out_final);
    agg_item_fuse_kernel<<<(N_ITEMS + 3) / 4, 256, 0, stream>>>(
        user_emb, off_item, row_sorted, out_item_kg, g1, g2,
        out_item_int, out_final);
    agg_user_kernel<<<(N_USERS + 3) / 4, 256, 0, stream>>>(
        out_final, off_user, col_sorted, out_user);
}